// Round 5
// baseline (189.996 us; speedup 1.0000x reference)
//
#include <hip/hip_runtime.h>
#include <hip/hip_bf16.h>
#include <math.h>

// x: [D=32, N=9216] fp32. 3 iters: w(i,j)=exp(3*<x_i,x_j>),
// x[:,j] <- 0.5*sum_i w*x[:,i]/sum_i w + 0.5*x[:,j]
// Output: [x3][x1][x2][x3].
// bf16 MFMA flash-style, transpose-free (sigma-permuted QK A-rows put S in
// PV-B fragment layout; w=exp packed in-register). R5: 128-thread blocks,
// 1152-block grid (~18 waves/CU) + atomic reduction (no partial buffers).

#define D 32
#define NPIX 9216
#define NSPLIT 16            // i-split; grid = 72*16 = 1152 blocks
#define JB 128               // j per block = 2 waves * 64 j
#define NJB (NPIX / JB)      // 72
#define IPB (NPIX / NSPLIT)  // 576 i per block
#define ICH 64               // i staged per barrier (2 sub-chunks of 32)
#define XST 56               // LDS row stride (shorts)
#define TS  40               // combine transpose tile stride (shorts)

typedef __attribute__((ext_vector_type(8))) short short8;
typedef __attribute__((ext_vector_type(4))) short short4v;
typedef __attribute__((ext_vector_type(4))) float f32x4;

#if __has_builtin(__builtin_amdgcn_exp2f)
#define EXP2F __builtin_amdgcn_exp2f
#else
#define EXP2F exp2f
#endif

#define C3 4.32808512266689f   // 3 * log2(e)

__device__ __forceinline__ unsigned pack2_bf16(float a, float b) {
    union { __hip_bfloat162 h2; unsigned u; } c;
    c.h2 = __float22bfloat162_rn(make_float2(a, b));
    return c.u;
}
__device__ __forceinline__ short pack1_bf16(float a) {
    union { __hip_bfloat16 h; unsigned short s; } c;
    c.h = __float2bfloat16(a);
    return (short)c.s;
}

// num[d][j] += sum_{i in split} w(i,j)*x[d][i]; den[j] likewise (atomics).
__global__ __launch_bounds__(128, 4) void accum_kernel(
    const short* __restrict__ xb,    // bf16 bits [D][NPIX]
    const short* __restrict__ xbT,   // bf16 bits [NPIX][D]
    float* __restrict__ num,         // [D][NPIX], pre-zeroed
    float* __restrict__ den)         // [NPIX], pre-zeroed
{
    // xiT_s rows sigma-permuted: QK mfma on rows m / 16+m yields C regs holding
    // i = quad*8+{0..3} / {4..7} == the PV B-fragment's k distribution.
    __shared__ __align__(16) short xiT_s[2][32 * XST];   // [chunk][sigma(i)][d]
    __shared__ __align__(16) short xi_s [2][32 * XST];   // [chunk][d][i]

    const int t = threadIdx.x;
    const int wid = t >> 6, lane = t & 63, quad = lane >> 4, m = lane & 15;
    const int bj = blockIdx.x % NJB, bi = blockIdx.x / NJB;
    const int j0 = bj * JB + wid * 64;
    const int i0b = bi * IPB;

    // Hoisted QK B-frags (j side): B[k=d][n=j_local]; lane: n=m, k=quad*8+e
    short8 bfrag[4];
#pragma unroll
    for (int jt = 0; jt < 4; ++jt)
        bfrag[jt] = *(const short8*)&xbT[(size_t)(j0 + jt * 16 + m) * D + quad * 8];

    f32x4 acc[2][4] = {};                       // [d-tile][j-tile], C-layout
    float dacc[4] = {0.f, 0.f, 0.f, 0.f};

    // staging coords (128 threads): per k in {0,1}: row = t>>2 (0..31), col=(t&3)*8
    const int srow = t >> 2, scol = (t & 3) * 8;
    const int sgm = ((srow & 4) << 2) + ((srow >> 3) << 2) + (srow & 3);  // sigma(row)

    for (int ic = 0; ic < IPB; ic += ICH) {
        const int i0 = i0b + ic;
        __syncthreads();
#pragma unroll
        for (int k = 0; k < 2; ++k) {
            // xbT rows i0 + k*32 + srow -> chunk k, permuted row
            *(short8*)&xiT_s[k][sgm * XST + scol] =
                *(const short8*)&xbT[(size_t)(i0 + k * 32 + srow) * D + scol];
            // xb row d=srow, i-cols i0 + k*32 + scol
            *(short8*)&xi_s[k][srow * XST + scol] =
                *(const short8*)&xb[srow * NPIX + i0 + k * 32 + scol];
        }
        __syncthreads();

#pragma unroll
        for (int h = 0; h < 2; ++h) {
            short8 aT0 = *(const short8*)&xiT_s[h][m * XST + quad * 8];
            short8 aT1 = *(const short8*)&xiT_s[h][(16 + m) * XST + quad * 8];
            short8 aV0 = *(const short8*)&xi_s[h][m * XST + quad * 8];
            short8 aV1 = *(const short8*)&xi_s[h][(16 + m) * XST + quad * 8];

#pragma unroll
            for (int jt = 0; jt < 4; ++jt) {
                f32x4 z = {0.f, 0.f, 0.f, 0.f};
                // s0 regs r: S[i=quad*8+r][j=m]; s1: S[i=quad*8+4+r][j=m]
                f32x4 s0 = __builtin_amdgcn_mfma_f32_16x16x32_bf16(aT0, bfrag[jt], z, 0, 0, 0);
                f32x4 s1 = __builtin_amdgcn_mfma_f32_16x16x32_bf16(aT1, bfrag[jt], z, 0, 0, 0);

                float w[8];
#pragma unroll
                for (int r = 0; r < 4; ++r) { w[r]     = EXP2F(C3 * s0[r]);
                                              w[4 + r] = EXP2F(C3 * s1[r]); }
                // pairwise tree to shorten dacc chain
                float p0 = (w[0] + w[1]) + (w[2] + w[3]);
                float p1 = (w[4] + w[5]) + (w[6] + w[7]);
                dacc[jt] += p0 + p1;

                // In-register B-frag of w: element e = i-offset quad*8+e
                union { short8 s; unsigned u[4]; } wb;
                wb.u[0] = pack2_bf16(w[0], w[1]);
                wb.u[1] = pack2_bf16(w[2], w[3]);
                wb.u[2] = pack2_bf16(w[4], w[5]);
                wb.u[3] = pack2_bf16(w[6], w[7]);

                // num[d][j] += x[d][i] * w[i][j]  (M=d, N=j, K=i=32)
                acc[0][jt] = __builtin_amdgcn_mfma_f32_16x16x32_bf16(aV0, wb.s, acc[0][jt], 0, 0, 0);
                acc[1][jt] = __builtin_amdgcn_mfma_f32_16x16x32_bf16(aV1, wb.s, acc[1][jt], 0, 0, 0);
            }
        }
    }

    // Commit split's partials via device atomics (coalesced addresses per quad-row).
#pragma unroll
    for (int dt = 0; dt < 2; ++dt)
#pragma unroll
        for (int jt = 0; jt < 4; ++jt)
#pragma unroll
            for (int r = 0; r < 4; ++r)
                atomicAdd(&num[(dt * 16 + quad * 4 + r) * NPIX + j0 + jt * 16 + m],
                          acc[dt][jt][r]);
#pragma unroll
    for (int jt = 0; jt < 4; ++jt) {
        float v = dacc[jt];
        v += __shfl_xor(v, 16, 64);
        v += __shfl_xor(v, 32, 64);
        if (quad == 0) atomicAdd(&den[j0 + jt * 16 + m], v);
    }
}

// v = 0.5*num/den + 0.5*xin (or v=xin if !do_ms). Writes xout/xfinal (fp32),
// xb (bf16 [D][N]), xbT (bf16 [N][D] via LDS transpose). Re-zeroes num/den.
// 288 blocks x 256: thread t: i = blk*32 + (t&31), d = (t>>5)*4 .. +3.
__global__ __launch_bounds__(256) void combine_kernel(
    const float* __restrict__ xin,
    float* __restrict__ num, float* __restrict__ den,
    float* __restrict__ xout, float* __restrict__ xfinal,
    short* __restrict__ xb, short* __restrict__ xbT, int do_ms)
{
    __shared__ __align__(16) short tile[32 * TS];   // [i_local][d]
    const int t = threadIdx.x;
    const int il = t & 31, q = t >> 5;
    const int i = blockIdx.x * 32 + il;
    const int d0 = q * 4;

    float inv = 0.f;
    if (do_ms) inv = 0.5f / den[i];

#pragma unroll
    for (int dd = 0; dd < 4; ++dd) {
        const int d = d0 + dd;
        const int idx = d * NPIX + i;
        float v;
        if (do_ms) {
            v = num[idx] * inv + 0.5f * xin[idx];
            xout[idx] = v;
            if (xfinal) xfinal[idx] = v;
        } else {
            v = xin[idx];
        }
        num[idx] = 0.f;                 // re-zero for next accum
        short b = pack1_bf16(v);
        xb[idx] = b;
        tile[il * TS + d] = b;
    }
    __syncthreads();
    if (t < 32) den[blockIdx.x * 32 + t] = 0.f;   // all den reads done
    // xbT rows: thread t writes 4 shorts (8 B)
    const int i2 = t >> 3, dc = (t & 7) * 4;
    *(short4v*)&xbT[(size_t)(blockIdx.x * 32 + i2) * D + dc] =
        *(const short4v*)&tile[i2 * TS + dc];
}

extern "C" void kernel_launch(void* const* d_in, const int* in_sizes, int n_in,
                              void* d_out, int out_size, void* d_ws, size_t ws_size,
                              hipStream_t stream)
{
    const float* x0 = (const float*)d_in[0];
    float* out = (float*)d_out;              // [x3][x1][x2][x3]
    const size_t slot = (size_t)D * NPIX;

    float* num = (float*)d_ws;               // D*NPIX f32
    float* den = num + slot;                 // NPIX f32
    short* xb  = (short*)(den + NPIX);       // D*NPIX bf16
    short* xbT = xb + slot;                  // NPIX*D bf16

    // convert x0 -> xb/xbT, zero num/den
    combine_kernel<<<dim3(NPIX / 32), dim3(256), 0, stream>>>(
        x0, num, den, nullptr, nullptr, xb, xbT, 0);

    for (int t = 0; t < 3; ++t) {
        accum_kernel<<<dim3(NJB * NSPLIT), dim3(128), 0, stream>>>(xb, xbT, num, den);
        const float* xin = (t == 0) ? x0 : (out + (size_t)t * slot);
        combine_kernel<<<dim3(NPIX / 32), dim3(256), 0, stream>>>(
            xin, num, den, out + (size_t)(t + 1) * slot,
            (t == 2) ? out : nullptr, xb, xbT, 1);
    }
}